// Round 5
// baseline (450.428 us; speedup 1.0000x reference)
//
#include <hip/hip_runtime.h>
#include <hip/hip_bf16.h>
#include <stdint.h>

// AttentionBlock: x[32,64,64,256] fp32; attention over W axis per (b,h) row.
// Folded form (softmax identities + associativity):
//   T   = x·Wqk + 1·c          Wqk = Wq·Wk^T,  c = bq·Wk^T   (row-const terms drop in softmax)
//   S   = T·x^T                (double scale folded: 1/(256·16·sqrt(.5)))
//   P   = softmax(S)           (rows sum to 1)
//   V   = x·Wvo                Wvo = Wv·Wo
//   out = P·V + 1·bvo + x      bvo = bv·Wo + bo
// R5: ts/vt tiles moved from LDS to per-row GLOBAL scratch (g_t row-major
// [bh][tok][ch], g_v transposed [bh][ch][tok]). The cross-wave T/V handoff is
// block-private and read one barrier after the write -> L2-hot. LDS shrinks
// 79.9KB -> 43.0KB (xs + ps only) => 3 blocks/CU = 12 waves/CU (+50% latency
// hiding vs R4's 2 blocks). vt no longer aliases ts, so the T-GEMM and V-GEMM
// share one barrier region: 2 barriers total (was 4). ps is wave-private
// (write->read same wave, lgkmcnt only). All MFMA fragment addresses keep the
// R4-verified 16B patterns; numerics identical (same bf16 round-trips).

typedef __bf16 bf16x8 __attribute__((ext_vector_type(8)));
typedef __bf16 bf16x4 __attribute__((ext_vector_type(4)));
typedef float f32x4 __attribute__((ext_vector_type(4)));

#define C 256
#define WTOK 64
#define CP 264   // xs row stride (bf16): 528 B = 132 dw (== 4 mod 32: benign spread)
#define PP 72    // ps row stride: 144 B = 36 dw (== 4 mod 32)
#define VSTRIDE 64   // g_v row stride (tok), global: 128B rows, L2-line aligned

// Device-global weight staging + T/V scratch (no d_ws dependence).
__device__ float  g_wT[2 * 65536];   // z=0: WqT, z=1: WvT  (d[m*256+k] = W[k][m]) fp32
__device__ __bf16 g_wqk[65536];      // g_wqk[n*256+k] = Wqk[k][n] = sum_m Wq[k][m]*Wk[n][m]
__device__ __bf16 g_wvo[65536];      // g_wvo[n*256+k] = Wvo[k][n] = sum_m Wv[k][m]*Wo[m][n]
__device__ float  g_c[256];          // c[n]   = sum_m bq[m]*Wk[n][m]
__device__ float  g_bvo[256];        // bvo[n] = sum_k bv[k]*Wo[k][n] + bo[n]
__device__ __bf16 g_t[2048 * WTOK * C];      // T  [bh][tok][ch]   64 MB
__device__ __bf16 g_v[2048 * C * VSTRIDE];   // V^T [bh][ch][tok]  64 MB

__device__ __forceinline__ bf16x8 ld8(const __bf16* p) {
  return *reinterpret_cast<const bf16x8*>(p);
}

// ---- kernel 1: fp32 transpose of Wq, Wv into g_wT
__global__ __launch_bounds__(256) void trans_kernel(
    const float* __restrict__ wq, const float* __restrict__ wv) {
  __shared__ float tile[32][33];
  const float* src = (blockIdx.z == 0) ? wq : wv;
  float* d = &g_wT[0] + (size_t)blockIdx.z * 65536;
  const int tx = threadIdx.x, ty = threadIdx.y;
  const int k0 = blockIdx.x * 32;   // src row block
  const int m0 = blockIdx.y * 32;   // src col block
  for (int i = 0; i < 4; ++i)
    tile[ty + 8 * i][tx] = src[(size_t)(k0 + ty + 8 * i) * 256 + m0 + tx];
  __syncthreads();
  for (int i = 0; i < 4; ++i)
    d[(size_t)(m0 + ty + 8 * i) * 256 + k0 + tx] = tile[tx][ty + 8 * i];
}

// ---- kernel 2: fold products + folded biases.
// blockIdx.y==0: Wqk (uses WqT, wk) + g_c. ==1: Wvo (uses WvT, wo) + g_bvo.
__global__ __launch_bounds__(256) void fold_kernel(
    const float* __restrict__ wk, const float* __restrict__ wo,
    const float* __restrict__ bq, const float* __restrict__ bv,
    const float* __restrict__ bo) {
  const int n = blockIdx.x;
  const int k = threadIdx.x;
  if (blockIdx.y == 0) {
    const float* a = &g_wT[0];             // WqT: a[m*256+k] = Wq[k][m]
    float acc = 0.f, c = 0.f;
    #pragma unroll 8
    for (int m = 0; m < 256; ++m) {
      const float w = wk[n * 256 + m];     // Wk[n][m], lane-uniform
      acc += a[m * 256 + k] * w;
      c += bq[m] * w;
    }
    g_wqk[n * 256 + k] = (__bf16)acc;
    if (k == 0) g_c[n] = c;
  } else {
    const float* a = &g_wT[65536];         // WvT
    float acc = 0.f, bb = 0.f;
    #pragma unroll 8
    for (int m = 0; m < 256; ++m) {
      const float w = wo[m * 256 + n];     // Wo[m][n], lane-uniform
      acc += a[m * 256 + k] * w;
      bb += bv[m] * w;
    }
    g_wvo[n * 256 + k] = (__bf16)acc;
    if (k == 0) g_bvo[n] = bb + bo[n];
  }
}

// ---- fused per-(b,h)-row kernel
__global__ __launch_bounds__(256, 3) void attn_fused_kernel(
    const float* __restrict__ x, float* __restrict__ out) {
  // LDS: xs[64][CP] (16896 elems) | ps[64][PP] (4608 elems) = 21504 elems = 43008 B
  // -> 3 blocks/CU (LDS cap 3.8, VGPR-capped at 3 via launch_bounds).
  __shared__ __align__(16) __bf16 smem[21504];
  __bf16* xs = smem;            // x row, bf16: live whole kernel
  __bf16* ps = smem + 16896;    // softmax output, wave-private rows

  const int tid = threadIdx.x;
  const int wv = tid >> 6;
  const int lane = tid & 63;
  const int quad = lane >> 4;
  const int l16 = lane & 15;
  const int bh = blockIdx.x;  // 0..2047
  const float* xrow = x + (size_t)bh * (WTOK * C);
  __bf16* trow = g_t + (size_t)bh * (WTOK * C);      // T  [tok][ch]
  __bf16* vrow = g_v + (size_t)bh * (C * VSTRIDE);   // V^T [ch][tok]

  // Phase 0: stage x row [64][256] fp32 -> xs bf16
  for (int it = 0; it < 16; ++it) {
    const int chunk = tid + it * 256;     // 0..4095
    const int row = chunk >> 6;           // 0..63
    const int c4 = (chunk & 63) << 2;     // 0..252
    const float4 v = *reinterpret_cast<const float4*>(xrow + row * 256 + c4);
    bf16x4 b;
    b[0] = (__bf16)v.x; b[1] = (__bf16)v.y; b[2] = (__bf16)v.z; b[3] = (__bf16)v.w;
    *reinterpret_cast<bf16x4*>(xs + row * CP + c4) = b;
  }
  __syncthreads();  // B1: xs ready

  const int nb = wv * 64;
  const int i0 = wv * 16;

  // Phase 1a: T^T = Wqk^T · x^T  (wave: its 64-ch n-span x all 64 tokens)
  // D[m][t] reg r: ch = nb+m*16+quad*4+r, tok = t*16+l16 -> packed 8B global store.
  // Per (t), the 4 m-stores of a wave fully dirty the 128B L2 line segment.
  {
    f32x4 D[4][4];
    const f32x4 zero = {0.f, 0.f, 0.f, 0.f};
    for (int m = 0; m < 4; ++m)
      for (int t = 0; t < 4; ++t) D[m][t] = zero;
    for (int kc = 0; kc < 8; ++kc) {
      const int ko = kc * 32 + quad * 8;
      bf16x8 a[4];
      for (int m = 0; m < 4; ++m)
        a[m] = ld8(g_wqk + (size_t)(nb + m * 16 + l16) * 256 + ko);
      for (int t = 0; t < 4; ++t) {
        bf16x8 b = ld8(xs + (t * 16 + l16) * CP + ko);
        for (int m = 0; m < 4; ++m)
          D[m][t] = __builtin_amdgcn_mfma_f32_16x16x32_bf16(a[m], b, D[m][t], 0, 0, 0);
      }
    }
    float4 cs[4];
    for (int m = 0; m < 4; ++m)
      cs[m] = *reinterpret_cast<const float4*>(g_c + nb + m * 16 + quad * 4);
    for (int m = 0; m < 4; ++m)
      for (int t = 0; t < 4; ++t) {
        bf16x4 v4;
        v4[0] = (__bf16)(D[m][t][0] + cs[m].x);
        v4[1] = (__bf16)(D[m][t][1] + cs[m].y);
        v4[2] = (__bf16)(D[m][t][2] + cs[m].z);
        v4[3] = (__bf16)(D[m][t][3] + cs[m].w);
        *reinterpret_cast<bf16x4*>(trow + (t * 16 + l16) * 256 + nb + m * 16 + quad * 4) = v4;
      }
  }

  // Phase 1b: V = x·Wvo  (same barrier region — vt no longer aliases ts)
  // D[m][nt] reg r: tok = m*16+quad*4+r, ch = nb+nt*16+l16 -> packed 8B V^T store.
  {
    f32x4 D[4][4];
    const f32x4 zero = {0.f, 0.f, 0.f, 0.f};
    for (int m = 0; m < 4; ++m)
      for (int nt = 0; nt < 4; ++nt) D[m][nt] = zero;
    for (int kc = 0; kc < 8; ++kc) {
      const int ko = kc * 32 + quad * 8;
      bf16x8 a[4];
      for (int m = 0; m < 4; ++m) a[m] = ld8(xs + (m * 16 + l16) * CP + ko);
      for (int nt = 0; nt < 4; ++nt) {
        bf16x8 b = ld8(g_wvo + (size_t)(nb + nt * 16 + l16) * 256 + ko);
        for (int m = 0; m < 4; ++m)
          D[m][nt] = __builtin_amdgcn_mfma_f32_16x16x32_bf16(a[m], b, D[m][nt], 0, 0, 0);
      }
    }
    for (int nt = 0; nt < 4; ++nt) {
      const int ch = nb + nt * 16 + l16;
      for (int m = 0; m < 4; ++m) {
        bf16x4 v4;
        for (int r = 0; r < 4; ++r) v4[r] = (__bf16)D[m][nt][r];
        *reinterpret_cast<bf16x4*>(vrow + ch * VSTRIDE + m * 16 + quad * 4) = v4;
      }
    }
  }
  __threadfence_block();
  __syncthreads();  // B2: T, V committed to L2 and visible to all waves

  // Phase 2: S^T = x_keys · T^T  (wave: all 64 keys x its 16 queries i0..i0+15)
  // A-frag: lane = x[key = nt*16+l16][ch ko..ko+7]      (xs row read)
  // B-frag: lane = T[q = i0+l16][ch ko..ko+7]           (global T row read, L2-hot)
  // S[nt] reg r: key = nt*16+quad*4+r, query = i0+l16
  f32x4 S[4];
  {
    const f32x4 zero = {0.f, 0.f, 0.f, 0.f};
    for (int nt = 0; nt < 4; ++nt) S[nt] = zero;
    bf16x8 qb[8];
    for (int kc = 0; kc < 8; ++kc)
      qb[kc] = ld8(trow + (i0 + l16) * 256 + kc * 32 + quad * 8);
    for (int nt = 0; nt < 4; ++nt)
      for (int kc = 0; kc < 8; ++kc) {
        bf16x8 ka = ld8(xs + (nt * 16 + l16) * CP + kc * 32 + quad * 8);
        S[nt] = __builtin_amdgcn_mfma_f32_16x16x32_bf16(ka, qb[kc], S[nt], 0, 0, 0);
      }
  }

  // softmax for query q = i0+l16: 16 in-lane key-values + quad-combine (2 shfls each)
  const float SCALE = 1.0f / (256.0f * 16.0f * 0.70710678118654752f);
  {
    float p[16];
    float mx = -1e30f;
    for (int nt = 0; nt < 4; ++nt)
      for (int r = 0; r < 4; ++r) {
        p[nt * 4 + r] = S[nt][r] * SCALE;
        mx = fmaxf(mx, p[nt * 4 + r]);
      }
    mx = fmaxf(mx, __shfl_xor(mx, 16));
    mx = fmaxf(mx, __shfl_xor(mx, 32));
    float sum = 0.f;
    for (int i = 0; i < 16; ++i) {
      p[i] = __expf(p[i] - mx);
      sum += p[i];
    }
    sum += __shfl_xor(sum, 16);
    sum += __shfl_xor(sum, 32);
    const float invs = 1.0f / sum;
    for (int nt = 0; nt < 4; ++nt) {
      bf16x4 v4;
      for (int r = 0; r < 4; ++r) v4[r] = (__bf16)(p[nt * 4 + r] * invs);
      *reinterpret_cast<bf16x4*>(ps + (i0 + l16) * PP + nt * 16 + quad * 4) = v4;
    }
  }
  // ps rows i0..i0+15 are written and read by THIS wave only -> no barrier needed;
  // the compiler's lgkmcnt wait before the dependent ds_read suffices.

  // Phase 3: out^T = V^T · P^T  (wave: all 256 ch x its 16 queries)
  // A-frag: lane = V^T[ch = ct*16+l16][tok ko..ko+7]    (global V^T row read, L2-hot)
  // B-frag: lane = P^T[key ko..ko+7][q = i0+l16]        (ps row read)
  // Y[ct] reg r: ch = ct*16+quad*4+r, query = i0+l16 -> float4 epilogue
  {
    f32x4 Y[16];
    const f32x4 zero = {0.f, 0.f, 0.f, 0.f};
    for (int ct = 0; ct < 16; ++ct) Y[ct] = zero;
    bf16x8 pb[2];
    for (int kc = 0; kc < 2; ++kc)
      pb[kc] = ld8(ps + (i0 + l16) * PP + kc * 32 + quad * 8);
    #pragma unroll
    for (int ct = 0; ct < 16; ++ct) {
      #pragma unroll
      for (int kc = 0; kc < 2; ++kc) {
        bf16x8 va = ld8(vrow + (ct * 16 + l16) * VSTRIDE + kc * 32 + quad * 8);
        Y[ct] = __builtin_amdgcn_mfma_f32_16x16x32_bf16(va, pb[kc], Y[ct], 0, 0, 0);
      }
    }
    const int q = i0 + l16;
    const float* xr = xrow + q * 256;
    float* outr = out + ((size_t)bh * WTOK + q) * C;
    #pragma unroll
    for (int ct = 0; ct < 16; ++ct) {
      const int ch = ct * 16 + quad * 4;
      const float4 bv4 = *reinterpret_cast<const float4*>(g_bvo + ch);
      const float4 xres = *reinterpret_cast<const float4*>(xr + ch);
      float4 o;
      o.x = Y[ct][0] + bv4.x + xres.x;
      o.y = Y[ct][1] + bv4.y + xres.y;
      o.z = Y[ct][2] + bv4.z + xres.z;
      o.w = Y[ct][3] + bv4.w + xres.w;
      *reinterpret_cast<float4*>(outr + ch) = o;
    }
  }
}

extern "C" void kernel_launch(void* const* d_in, const int* in_sizes, int n_in,
                              void* d_out, int out_size, void* d_ws, size_t ws_size,
                              hipStream_t stream) {
  (void)in_sizes; (void)n_in; (void)out_size; (void)d_ws; (void)ws_size;
  const float* x  = (const float*)d_in[0];
  const float* Wq = (const float*)d_in[1];
  const float* bq = (const float*)d_in[2];
  const float* Wk = (const float*)d_in[3];
  const float* Wv = (const float*)d_in[5];
  const float* bv = (const float*)d_in[6];
  const float* Wo = (const float*)d_in[7];
  const float* bo = (const float*)d_in[8];
  float* out = (float*)d_out;

  hipLaunchKernelGGL(trans_kernel, dim3(8, 8, 2), dim3(32, 8, 1), 0, stream, Wq, Wv);
  hipLaunchKernelGGL(fold_kernel, dim3(256, 2, 1), dim3(256), 0, stream, Wk, Wo, bq, bv, bo);
  hipLaunchKernelGGL(attn_fused_kernel, dim3(2048), dim3(256), 0, stream, x, out);
}